// Round 13
// baseline (637.069 us; speedup 1.0000x reference)
//
#include <hip/hip_runtime.h>
#include <hip/hip_bf16.h>

// Mix2Layer: out[b,o] = sum_k relu(sum_i x[b,i]*w1[i,o,k] + b1[o,k]) * (sum_i x[b,i]*w2[i,o,k]) + b2[o]
// B=2048, DIN=2048, DOUT=2048, K=16.  N' = o*16+k (w row-major [DIN][32768]).
//
// Fast path (needs ws >= 264MB):
//   1) xcvt:   x fp32 -> bf16                  (8 MB)
//   2) wtrans: w[i][n'] fp32 -> wt[n'][i] bf16 (128 MB each)
//   3) mix2_gemm2b: 256x128 tile, BK=64, double-buffer (2x64KB), 16 waves
//      (4 waves/SIMD), ONE barrier + phase-old vmcnt(0) per 64-k phase.
//      amdgpu_waves_per_eu(4,4): LDS caps us at 1 block/CU = 4 waves/EU anyway,
//      so give the allocator the full 128-VGPR budget -> no spill (R12 spilled
//      ~100MB/dispatch at the compiler's default 64-VGPR/8-wave target).
// Fallback: round-1 in-kernel-transpose kernel (verified passing).

typedef __bf16 bf16;
typedef bf16 bf16x8 __attribute__((ext_vector_type(8)));
typedef bf16 bf16x4 __attribute__((ext_vector_type(4)));
typedef float f32x4 __attribute__((ext_vector_type(4)));

typedef __attribute__((address_space(1))) const void gco_void;
typedef __attribute__((address_space(3))) void lds_void;

#define DIN_   2048
#define DOUT_  2048
#define NP_    32768   // DOUT*K

__device__ __forceinline__ bf16x8 cvt8(f32x4 a, f32x4 b) {
    bf16x8 v;
    v[0] = (bf16)a[0]; v[1] = (bf16)a[1]; v[2] = (bf16)a[2]; v[3] = (bf16)a[3];
    v[4] = (bf16)b[0]; v[5] = (bf16)b[1]; v[6] = (bf16)b[2]; v[7] = (bf16)b[3];
    return v;
}

// ---------------- prep 1: x fp32 -> bf16 ----------------
__global__ __launch_bounds__(256)
void xcvt(const float* __restrict__ x, bf16* __restrict__ xb) {
    const size_t i = ((size_t)blockIdx.x * 256 + threadIdx.x) * 8;
    f32x4 a = *(const f32x4*)(x + i);
    f32x4 b = *(const f32x4*)(x + i + 4);
    *(bf16x8*)(xb + i) = cvt8(a, b);
}

// ---------------- prep 2: w[i][n'] fp32 -> wt[n'][i] bf16 ----------------
__global__ __launch_bounds__(256)
void wtrans(const float* __restrict__ w1, const float* __restrict__ w2,
            bf16* __restrict__ w1t, bf16* __restrict__ w2t) {
    __shared__ float s[64][65];
    const int t  = threadIdx.x;
    const int lr = t >> 4;      // 0..15
    const int lq = t & 15;      // 0..15
    const int n0 = blockIdx.x * 64;
    const int i0 = blockIdx.y * 64;
    const float* src = blockIdx.z ? w2 : w1;
    bf16*        dst = blockIdx.z ? w2t : w1t;
#pragma unroll
    for (int r = 0; r < 4; ++r) {
        const int il = lr + 16 * r;
        f32x4 v = *(const f32x4*)(src + (size_t)(i0 + il) * NP_ + n0 + lq * 4);
        s[il][lq * 4 + 0] = v[0]; s[il][lq * 4 + 1] = v[1];
        s[il][lq * 4 + 2] = v[2]; s[il][lq * 4 + 3] = v[3];
    }
    __syncthreads();
#pragma unroll
    for (int r = 0; r < 4; ++r) {
        const int nl = lr + 16 * r;
        bf16x4 o;
        o[0] = (bf16)s[lq * 4 + 0][nl]; o[1] = (bf16)s[lq * 4 + 1][nl];
        o[2] = (bf16)s[lq * 4 + 2][nl]; o[3] = (bf16)s[lq * 4 + 3][nl];
        *(bf16x4*)(dst + (size_t)(n0 + nl) * DIN_ + i0 + lq * 4) = o;
    }
}

// ---------------- main: 256x128 tile, BK=64, double-buffer, 16 waves ----------------
// 32 K-tiles of 64 k; 2 LDS buffers (64KB):
//   buf = t&1: [A 256x64k 32KB][B1 128x64k 16KB][B2 128x64k 16KB]
// rows 128B = 8 slots of 16B; phys slot p of row r holds data slot p^(r&7)
// (pre-swizzled global source; fragment reads apply the same XOR -> 2 lanes/bank).
// Per phase t: vmcnt(0) [S(t) issued a full phase ago -> ~free]; barrier;
// STG(t+1) [4 loads/thread]; 16 ds_read_b128 + 32 MFMA (compiler-counted lgkm).
__global__ __launch_bounds__(1024, 1) __attribute__((amdgpu_waves_per_eu(4, 4)))
void mix2_gemm2b(const bf16* __restrict__ xb, const bf16* __restrict__ w1t,
                 const bf16* __restrict__ w2t, const float* __restrict__ b1,
                 const float* __restrict__ b2, float* __restrict__ out)
{
    __shared__ alignas(16) char lds[131072];

    const int tid  = threadIdx.x;
    const int lane = tid & 63;
    const int wid  = tid >> 6;     // 0..15
    const int wm   = wid >> 2;     // 0..3  (64-row slab)
    const int wn   = wid & 3;      // 0..3  (32-col slab)
    const int lk   = lane & 15;
    const int lg   = lane >> 4;

    const int nwg = gridDim.x;     // 2048
    const int bid = (blockIdx.x & 7) * (nwg >> 3) + (blockIdx.x >> 3);
    const int mt  = bid & 7;       // 8 m-tiles of 256
    const int nt  = bid >> 3;      // 256 n-panels of 128

    // staging: chunk c -> row=c>>3, phys slot=c&7 holds data slot (c&7)^(row&7)
    const int srow = tid >> 3;                 // 0..127
    const int sswz = ((tid & 7) ^ (srow & 7)) * 8;
    const bf16* gA0 = xb  + (size_t)(mt * 256 + srow) * DIN_ + sswz;  // rows 0..127
    const bf16* gA1 = gA0 + (size_t)128 * DIN_;                        // rows 128..255
    const bf16* gB1 = w1t + (size_t)(nt * 128 + srow) * DIN_ + sswz;
    const bf16* gB2 = w2t + (size_t)(nt * 128 + srow) * DIN_ + sswz;

    // fragment read offsets (bytes within a buffer), per k-half h2:
    // byte = row*128 + ((h2*4+lg) ^ (row&7))*16
    int aoff[4][2], boff[2][2];
#pragma unroll
    for (int fm = 0; fm < 4; ++fm)
#pragma unroll
        for (int h2 = 0; h2 < 2; ++h2) {
            const int row = wm * 64 + fm * 16 + lk;
            aoff[fm][h2] = row * 128 + (((h2 * 4 + lg) ^ (row & 7)) << 4);
        }
#pragma unroll
    for (int fn = 0; fn < 2; ++fn)
#pragma unroll
        for (int h2 = 0; h2 < 2; ++h2) {
            const int row = wn * 32 + fn * 16 + lk;
            boff[fn][h2] = 32768 + row * 128 + (((h2 * 4 + lg) ^ (row & 7)) << 4);
        }

    f32x4 acc1[4][2], acc2[4][2];
#pragma unroll
    for (int i = 0; i < 4; ++i)
#pragma unroll
        for (int j = 0; j < 2; ++j) {
            acc1[i][j] = (f32x4){0.f, 0.f, 0.f, 0.f};
            acc2[i][j] = (f32x4){0.f, 0.f, 0.f, 0.f};
        }

    auto STG = [&](int t) {        // 4 gload_lds per thread into buf t&1
        char* r = lds + (t & 1) * 65536;
        const int koff = t * 64;
        __builtin_amdgcn_global_load_lds((gco_void*)(gA0 + koff), (lds_void*)(r + tid * 16),          16, 0, 0);
        __builtin_amdgcn_global_load_lds((gco_void*)(gA1 + koff), (lds_void*)(r + 16384 + tid * 16),  16, 0, 0);
        __builtin_amdgcn_global_load_lds((gco_void*)(gB1 + koff), (lds_void*)(r + 32768 + tid * 16),  16, 0, 0);
        __builtin_amdgcn_global_load_lds((gco_void*)(gB2 + koff), (lds_void*)(r + 49152 + tid * 16),  16, 0, 0);
    };

    auto COMPUTE = [&](const char* r) {   // 16 ds_read_b128 + 32 MFMA (2 k-halves)
#pragma unroll
        for (int h2 = 0; h2 < 2; ++h2) {
            bf16x8 a[4], u[2], v[2];
#pragma unroll
            for (int fn = 0; fn < 2; ++fn) {
                u[fn] = *(const bf16x8*)(r + boff[fn][h2]);
                v[fn] = *(const bf16x8*)(r + boff[fn][h2] + 16384);
            }
#pragma unroll
            for (int fm = 0; fm < 4; ++fm) a[fm] = *(const bf16x8*)(r + aoff[fm][h2]);
            __builtin_amdgcn_s_setprio(1);
#pragma unroll
            for (int fm = 0; fm < 4; ++fm)
#pragma unroll
                for (int fn = 0; fn < 2; ++fn) {
                    acc1[fm][fn] = __builtin_amdgcn_mfma_f32_16x16x32_bf16(a[fm], u[fn], acc1[fm][fn], 0, 0, 0);
                    acc2[fm][fn] = __builtin_amdgcn_mfma_f32_16x16x32_bf16(a[fm], v[fn], acc2[fm][fn], 0, 0, 0);
                }
            __builtin_amdgcn_s_setprio(0);
        }
    };

#define SYNC() do { asm volatile("s_waitcnt vmcnt(0)" ::: "memory"); \
    __builtin_amdgcn_s_barrier(); __builtin_amdgcn_sched_barrier(0); } while (0)

    const char* buf0 = lds;
    const char* buf1 = lds + 65536;

    // prologue: stage tile 0
    STG(0);

    // phases 0..29 in pairs; each phase stages the next tile
#pragma unroll 1
    for (int tt = 0; tt < 15; ++tt) {
        const int t = tt * 2;
        SYNC(); STG(t + 1); COMPUTE(buf0);
        SYNC(); STG(t + 2); COMPUTE(buf1);
    }
    // t = 30 (stage S(31)), t = 31
    SYNC(); STG(31); COMPUTE(buf0);
    SYNC();          COMPUTE(buf1);

#undef SYNC

    // ---- epilogue: k-reduce via shfl_xor, cols lane&15 = 16 k's of one o ----
    const int obase = nt * 8 + wn * 2;
#pragma unroll
    for (int fn = 0; fn < 2; ++fn) {
        const int o = obase + fn;
        const float bb1 = b1[(size_t)o * 16 + lk];
        const float bb2 = b2[o];
#pragma unroll
        for (int fm = 0; fm < 4; ++fm) {
#pragma unroll
            for (int j = 0; j < 4; ++j) {
                float g = fmaxf(acc1[fm][fn][j] + bb1, 0.f);
                float p = g * acc2[fm][fn][j];
                p += __shfl_xor(p, 1);
                p += __shfl_xor(p, 2);
                p += __shfl_xor(p, 4);
                p += __shfl_xor(p, 8);
                if (lk == 0) {
                    const int brow = mt * 256 + wm * 64 + fm * 16 + lg * 4 + j;
                    out[(size_t)brow * DOUT_ + o] = p + bb2;
                }
            }
        }
    }
}

// ---------------- fallback: round-1 kernel (verified passing) ----------------
__global__ __launch_bounds__(512)
void mix2_fused_direct(const float* __restrict__ x, const float* __restrict__ w1,
                       const float* __restrict__ b1, const float* __restrict__ w2,
                       const float* __restrict__ b2, float* __restrict__ out)
{
    __shared__ alignas(16) char lds[2 * 49152];

    const int tid  = threadIdx.x;
    const int lane = tid & 63;
    const int wid  = tid >> 6;
    const int wm   = wid >> 2;
    const int wn   = wid & 3;

    const int nwg = gridDim.x;
    const int bid = (blockIdx.x & 7) * (nwg >> 3) + (blockIdx.x >> 3);
    const int mt  = bid & 15;
    const int nt  = bid >> 4;

    const int lk  = lane & 15;
    const int lg  = lane >> 4;
    const int swz = (lane & 7) << 4;

    const int a_row  = tid >> 3;
    const int a_col8 = tid & 7;
    const int b_ib = ((tid >> 5) & 15) << 2;
    const int b_nb = (tid & 31) << 2;

    const float* pa  = x  + (size_t)(mt * 128 + a_row) * DIN_ + a_col8 * 8;
    const float* pb1 = w1 + (size_t)b_ib * NP_ + (size_t)nt * 128 + b_nb;
    const float* pb2 = w2 + (size_t)b_ib * NP_ + (size_t)nt * 128 + b_nb;

    const int aswz   = (a_col8 * 16) ^ ((a_row & 7) << 4);
    const int aoffw0 = a_row * 128 + aswz;
    const int aoffw1 = (a_row + 64) * 128 + aswz;

    int aoff[4], boff1[2], boff2[2];
#pragma unroll
    for (int fm = 0; fm < 4; ++fm) aoff[fm] = (wm * 64 + fm * 16 + lk) * 128;
#pragma unroll
    for (int fn = 0; fn < 2; ++fn) {
        const int n = wn * 32 + fn * 16 + lk;
        boff1[fn] = 16384 + n * 128;
        boff2[fn] = 32768 + n * 128;
    }
    const int kp0 = (lg * 16) ^ swz;
    const int kp1 = (64 + lg * 16) ^ swz;

    f32x4 acc1[4][2], acc2[4][2];
#pragma unroll
    for (int i = 0; i < 4; ++i)
#pragma unroll
        for (int j = 0; j < 2; ++j) {
            acc1[i][j] = (f32x4){0.f, 0.f, 0.f, 0.f};
            acc2[i][j] = (f32x4){0.f, 0.f, 0.f, 0.f};
        }

    f32x4 rA[4], rB1[4], rB2[4];

    auto LOAD = [&](int kt) {
        const float* a0 = pa + kt * 64;
        rA[0] = *(const f32x4*)(a0);
        rA[1] = *(const f32x4*)(a0 + 4);
        rA[2] = *(const f32x4*)(a0 + (size_t)64 * DIN_);
        rA[3] = *(const f32x4*)(a0 + (size_t)64 * DIN_ + 4);
        const float* q1 = pb1 + (size_t)kt * 64 * NP_;
        const float* q2 = pb2 + (size_t)kt * 64 * NP_;
#pragma unroll
        for (int j = 0; j < 4; ++j) {
            rB1[j] = *(const f32x4*)(q1 + (size_t)j * NP_);
            rB2[j] = *(const f32x4*)(q2 + (size_t)j * NP_);
        }
    };

    auto STORE = [&](char* s) {
        *(bf16x8*)(s + aoffw0) = cvt8(rA[0], rA[1]);
        *(bf16x8*)(s + aoffw1) = cvt8(rA[2], rA[3]);
        char* s1 = s + 16384;
        char* s2 = s + 32768;
#pragma unroll
        for (int c = 0; c < 4; ++c) {
            const int n   = b_nb + c;
            const int off = n * 128 + ((b_ib * 2) ^ ((n & 7) << 4));
            bf16x4 v1, v2;
            v1[0] = (bf16)rB1[0][c]; v1[1] = (bf16)rB1[1][c];
            v1[2] = (bf16)rB1[2][c]; v1[3] = (bf16)rB1[3][c];
            v2[0] = (bf16)rB2[0][c]; v2[1] = (bf16)rB2[1][c];
            v2[2] = (bf16)rB2[2][c]; v2[3] = (bf16)rB2[3][c];
            *(bf16x4*)(s1 + off) = v1;
            *(bf16x4*)(s2 + off) = v2;
        }
    };

    auto COMPUTE = [&](const char* s) {
#pragma unroll
        for (int kb = 0; kb < 2; ++kb) {
            const int kp = kb ? kp1 : kp0;
            bf16x8 a[4], u[2], v[2];
#pragma unroll
            for (int fm = 0; fm < 4; ++fm) a[fm] = *(const bf16x8*)(s + aoff[fm] + kp);
#pragma unroll
            for (int fn = 0; fn < 2; ++fn) u[fn] = *(const bf16x8*)(s + boff1[fn] + kp);
#pragma unroll
            for (int fn = 0; fn < 2; ++fn) v[fn] = *(const bf16x8*)(s + boff2[fn] + kp);
#pragma unroll
            for (int fm = 0; fm < 4; ++fm)
#pragma unroll
                for (int fn = 0; fn < 2; ++fn) {
                    acc1[fm][fn] = __builtin_amdgcn_mfma_f32_16x16x32_bf16(a[fm], u[fn], acc1[fm][fn], 0, 0, 0);
                    acc2[fm][fn] = __builtin_amdgcn_mfma_f32_16x16x32_bf16(a[fm], v[fn], acc2[fm][fn], 0, 0, 0);
                }
        }
    };

    char* buf0 = lds;
    char* buf1 = lds + 49152;

    LOAD(0);
    STORE(buf0);
    __syncthreads();

    for (int kt = 0; kt < 32; ++kt) {
        if (kt + 1 < 32) LOAD(kt + 1);
        COMPUTE((kt & 1) ? buf1 : buf0);
        if (kt + 1 < 32) {
            STORE((kt & 1) ? buf0 : buf1);
            __syncthreads();
        }
    }

    const int obase = nt * 8 + wn * 2;
#pragma unroll
    for (int fn = 0; fn < 2; ++fn) {
        const int o = obase + fn;
        const float bb1 = b1[(size_t)o * 16 + lk];
        const float bb2 = b2[o];
#pragma unroll
        for (int fm = 0; fm < 4; ++fm) {
#pragma unroll
            for (int j = 0; j < 4; ++j) {
                float g = fmaxf(acc1[fm][fn][j] + bb1, 0.f);
                float p = g * acc2[fm][fn][j];
                p += __shfl_xor(p, 1);
                p += __shfl_xor(p, 2);
                p += __shfl_xor(p, 4);
                p += __shfl_xor(p, 8);
                if (lk == 0) {
                    const int brow = mt * 128 + wm * 64 + fm * 16 + lg * 4 + j;
                    out[(size_t)brow * DOUT_ + o] = p + bb2;
                }
            }
        }
    }
}

extern "C" void kernel_launch(void* const* d_in, const int* in_sizes, int n_in,
                              void* d_out, int out_size, void* d_ws, size_t ws_size,
                              hipStream_t stream) {
    (void)in_sizes; (void)n_in; (void)out_size;
    const float* x  = (const float*)d_in[0];
    const float* w1 = (const float*)d_in[1];
    const float* b1 = (const float*)d_in[2];
    const float* w2 = (const float*)d_in[3];
    const float* b2 = (const float*)d_in[4];
    float* out = (float*)d_out;

    const size_t XB   = (size_t)DIN_ * DIN_ * 2;            // 8 MB   (x bf16)
    const size_t WT   = (size_t)NP_ * DIN_ * 2;             // 128 MB (each wt)
    const size_t NEED = XB + 2 * WT;                        // 264 MB

    if (ws_size >= NEED) {
        bf16* xb  = (bf16*)d_ws;
        bf16* w1t = (bf16*)((char*)d_ws + XB);
        bf16* w2t = (bf16*)((char*)d_ws + XB + WT);
        hipLaunchKernelGGL(xcvt,   dim3(2048),       dim3(256),  0, stream, x, xb);
        hipLaunchKernelGGL(wtrans, dim3(512, 32, 2), dim3(256),  0, stream, w1, w2, w1t, w2t);
        hipLaunchKernelGGL(mix2_gemm2b, dim3(2048),  dim3(1024), 0, stream, xb, w1t, w2t, b1, b2, out);
    } else {
        hipLaunchKernelGGL(mix2_fused_direct, dim3(4096), dim3(512), 0, stream, x, w1, b1, w2, b2, out);
    }
}

// Round 14
// 635.281 us; speedup vs baseline: 1.0028x; 1.0028x over previous
//
#include <hip/hip_runtime.h>
#include <hip/hip_bf16.h>

// Mix2Layer: out[b,o] = sum_k relu(sum_i x[b,i]*w1[i,o,k] + b1[o,k]) * (sum_i x[b,i]*w2[i,o,k]) + b2[o]
// B=2048, DIN=2048, DOUT=2048, K=16.  N' = o*16+k (w row-major [DIN][32768]).
//
// Fast path (needs ws >= 264MB):
//   1) xcvt:   x fp32 -> bf16                  (8 MB)
//   2) wtrans: w[i][n'] fp32 -> wt[n'][i] bf16 (128 MB each)
//   3) mix2_gemm2b: 256x128 tile, BK=64, double-buffer (2x64KB), 16 waves
//      (4 waves/SIMD), ONE barrier + phase-old vmcnt(0) per 64-k phase.
//      sched_barrier(0) between the two k-halves stops the compiler from
//      hoisting all 16 ds_reads together (R12/R13 spilled ~100MB/dispatch
//      from 16 live fragments; capping the window at 8 fits 64 arch VGPRs).
// Fallback: round-1 in-kernel-transpose kernel (verified passing).

typedef __bf16 bf16;
typedef bf16 bf16x8 __attribute__((ext_vector_type(8)));
typedef bf16 bf16x4 __attribute__((ext_vector_type(4)));
typedef float f32x4 __attribute__((ext_vector_type(4)));

typedef __attribute__((address_space(1))) const void gco_void;
typedef __attribute__((address_space(3))) void lds_void;

#define DIN_   2048
#define DOUT_  2048
#define NP_    32768   // DOUT*K

__device__ __forceinline__ bf16x8 cvt8(f32x4 a, f32x4 b) {
    bf16x8 v;
    v[0] = (bf16)a[0]; v[1] = (bf16)a[1]; v[2] = (bf16)a[2]; v[3] = (bf16)a[3];
    v[4] = (bf16)b[0]; v[5] = (bf16)b[1]; v[6] = (bf16)b[2]; v[7] = (bf16)b[3];
    return v;
}

// ---------------- prep 1: x fp32 -> bf16 ----------------
__global__ __launch_bounds__(256)
void xcvt(const float* __restrict__ x, bf16* __restrict__ xb) {
    const size_t i = ((size_t)blockIdx.x * 256 + threadIdx.x) * 8;
    f32x4 a = *(const f32x4*)(x + i);
    f32x4 b = *(const f32x4*)(x + i + 4);
    *(bf16x8*)(xb + i) = cvt8(a, b);
}

// ---------------- prep 2: w[i][n'] fp32 -> wt[n'][i] bf16 ----------------
__global__ __launch_bounds__(256)
void wtrans(const float* __restrict__ w1, const float* __restrict__ w2,
            bf16* __restrict__ w1t, bf16* __restrict__ w2t) {
    __shared__ float s[64][65];
    const int t  = threadIdx.x;
    const int lr = t >> 4;      // 0..15
    const int lq = t & 15;      // 0..15
    const int n0 = blockIdx.x * 64;
    const int i0 = blockIdx.y * 64;
    const float* src = blockIdx.z ? w2 : w1;
    bf16*        dst = blockIdx.z ? w2t : w1t;
#pragma unroll
    for (int r = 0; r < 4; ++r) {
        const int il = lr + 16 * r;
        f32x4 v = *(const f32x4*)(src + (size_t)(i0 + il) * NP_ + n0 + lq * 4);
        s[il][lq * 4 + 0] = v[0]; s[il][lq * 4 + 1] = v[1];
        s[il][lq * 4 + 2] = v[2]; s[il][lq * 4 + 3] = v[3];
    }
    __syncthreads();
#pragma unroll
    for (int r = 0; r < 4; ++r) {
        const int nl = lr + 16 * r;
        bf16x4 o;
        o[0] = (bf16)s[lq * 4 + 0][nl]; o[1] = (bf16)s[lq * 4 + 1][nl];
        o[2] = (bf16)s[lq * 4 + 2][nl]; o[3] = (bf16)s[lq * 4 + 3][nl];
        *(bf16x4*)(dst + (size_t)(n0 + nl) * DIN_ + i0 + lq * 4) = o;
    }
}

// ---------------- main: 256x128 tile, BK=64, double-buffer, 16 waves ----------------
// 32 K-tiles of 64 k; 2 LDS buffers (64KB):
//   buf = t&1: [A 256x64k 32KB][B1 128x64k 16KB][B2 128x64k 16KB]
// rows 128B = 8 slots of 16B; phys slot p of row r holds data slot p^(r&7)
// (pre-swizzled global source; fragment reads apply the same XOR -> 2 lanes/bank).
// Per phase t: vmcnt(0) [S(t) issued a full phase ago -> ~free]; barrier;
// STG(t+1) [4 loads/thread]; 2 k-halves of {8 ds_read_b128 + 16 MFMA},
// sched_barrier(0)-fenced so only one half's fragments are live at a time.
__global__ __launch_bounds__(1024, 1)
void mix2_gemm2b(const bf16* __restrict__ xb, const bf16* __restrict__ w1t,
                 const bf16* __restrict__ w2t, const float* __restrict__ b1,
                 const float* __restrict__ b2, float* __restrict__ out)
{
    __shared__ alignas(16) char lds[131072];

    const int tid  = threadIdx.x;
    const int lane = tid & 63;
    const int wid  = tid >> 6;     // 0..15
    const int wm   = wid >> 2;     // 0..3  (64-row slab)
    const int wn   = wid & 3;      // 0..3  (32-col slab)
    const int lk   = lane & 15;
    const int lg   = lane >> 4;

    const int nwg = gridDim.x;     // 2048
    const int bid = (blockIdx.x & 7) * (nwg >> 3) + (blockIdx.x >> 3);
    const int mt  = bid & 7;       // 8 m-tiles of 256
    const int nt  = bid >> 3;      // 256 n-panels of 128

    // staging: chunk c -> row=c>>3, phys slot=c&7 holds data slot (c&7)^(row&7)
    const int srow = tid >> 3;                 // 0..127
    const int sswz = ((tid & 7) ^ (srow & 7)) * 8;
    const bf16* gA0 = xb  + (size_t)(mt * 256 + srow) * DIN_ + sswz;  // rows 0..127
    const bf16* gA1 = gA0 + (size_t)128 * DIN_;                        // rows 128..255
    const bf16* gB1 = w1t + (size_t)(nt * 128 + srow) * DIN_ + sswz;
    const bf16* gB2 = w2t + (size_t)(nt * 128 + srow) * DIN_ + sswz;

    // fragment read offsets (bytes within a buffer), per k-half h2:
    // byte = row*128 + ((h2*4+lg) ^ (row&7))*16
    int aoff[4][2], boff[2][2];
#pragma unroll
    for (int fm = 0; fm < 4; ++fm)
#pragma unroll
        for (int h2 = 0; h2 < 2; ++h2) {
            const int row = wm * 64 + fm * 16 + lk;
            aoff[fm][h2] = row * 128 + (((h2 * 4 + lg) ^ (row & 7)) << 4);
        }
#pragma unroll
    for (int fn = 0; fn < 2; ++fn)
#pragma unroll
        for (int h2 = 0; h2 < 2; ++h2) {
            const int row = wn * 32 + fn * 16 + lk;
            boff[fn][h2] = 32768 + row * 128 + (((h2 * 4 + lg) ^ (row & 7)) << 4);
        }

    f32x4 acc1[4][2], acc2[4][2];
#pragma unroll
    for (int i = 0; i < 4; ++i)
#pragma unroll
        for (int j = 0; j < 2; ++j) {
            acc1[i][j] = (f32x4){0.f, 0.f, 0.f, 0.f};
            acc2[i][j] = (f32x4){0.f, 0.f, 0.f, 0.f};
        }

    auto STG = [&](int t) {        // 4 gload_lds per thread into buf t&1
        char* r = lds + (t & 1) * 65536;
        const int koff = t * 64;
        __builtin_amdgcn_global_load_lds((gco_void*)(gA0 + koff), (lds_void*)(r + tid * 16),          16, 0, 0);
        __builtin_amdgcn_global_load_lds((gco_void*)(gA1 + koff), (lds_void*)(r + 16384 + tid * 16),  16, 0, 0);
        __builtin_amdgcn_global_load_lds((gco_void*)(gB1 + koff), (lds_void*)(r + 32768 + tid * 16),  16, 0, 0);
        __builtin_amdgcn_global_load_lds((gco_void*)(gB2 + koff), (lds_void*)(r + 49152 + tid * 16),  16, 0, 0);
    };

    auto COMPUTE = [&](const char* r) {   // 2 x {8 ds_read_b128 + 16 MFMA}, window-fenced
#pragma unroll
        for (int h2 = 0; h2 < 2; ++h2) {
            bf16x8 a[4], u[2], v[2];
#pragma unroll
            for (int fn = 0; fn < 2; ++fn) {
                u[fn] = *(const bf16x8*)(r + boff[fn][h2]);
                v[fn] = *(const bf16x8*)(r + boff[fn][h2] + 16384);
            }
#pragma unroll
            for (int fm = 0; fm < 4; ++fm) a[fm] = *(const bf16x8*)(r + aoff[fm][h2]);
            __builtin_amdgcn_s_setprio(1);
#pragma unroll
            for (int fm = 0; fm < 4; ++fm)
#pragma unroll
                for (int fn = 0; fn < 2; ++fn) {
                    acc1[fm][fn] = __builtin_amdgcn_mfma_f32_16x16x32_bf16(a[fm], u[fn], acc1[fm][fn], 0, 0, 0);
                    acc2[fm][fn] = __builtin_amdgcn_mfma_f32_16x16x32_bf16(a[fm], v[fn], acc2[fm][fn], 0, 0, 0);
                }
            __builtin_amdgcn_s_setprio(0);
            __builtin_amdgcn_sched_barrier(0);   // cap live-fragment window at one half
        }
    };

#define SYNC() do { asm volatile("s_waitcnt vmcnt(0)" ::: "memory"); \
    __builtin_amdgcn_s_barrier(); __builtin_amdgcn_sched_barrier(0); } while (0)

    const char* buf0 = lds;
    const char* buf1 = lds + 65536;

    // prologue: stage tile 0
    STG(0);

    // phases 0..29 in pairs; each phase stages the next tile
#pragma unroll 1
    for (int tt = 0; tt < 15; ++tt) {
        const int t = tt * 2;
        SYNC(); STG(t + 1); COMPUTE(buf0);
        SYNC(); STG(t + 2); COMPUTE(buf1);
    }
    // t = 30 (stage S(31)), t = 31
    SYNC(); STG(31); COMPUTE(buf0);
    SYNC();          COMPUTE(buf1);

#undef SYNC

    // ---- epilogue: k-reduce via shfl_xor, cols lane&15 = 16 k's of one o ----
    const int obase = nt * 8 + wn * 2;
#pragma unroll
    for (int fn = 0; fn < 2; ++fn) {
        const int o = obase + fn;
        const float bb1 = b1[(size_t)o * 16 + lk];
        const float bb2 = b2[o];
#pragma unroll
        for (int fm = 0; fm < 4; ++fm) {
#pragma unroll
            for (int j = 0; j < 4; ++j) {
                float g = fmaxf(acc1[fm][fn][j] + bb1, 0.f);
                float p = g * acc2[fm][fn][j];
                p += __shfl_xor(p, 1);
                p += __shfl_xor(p, 2);
                p += __shfl_xor(p, 4);
                p += __shfl_xor(p, 8);
                if (lk == 0) {
                    const int brow = mt * 256 + wm * 64 + fm * 16 + lg * 4 + j;
                    out[(size_t)brow * DOUT_ + o] = p + bb2;
                }
            }
        }
    }
}

// ---------------- fallback: round-1 kernel (verified passing) ----------------
__global__ __launch_bounds__(512)
void mix2_fused_direct(const float* __restrict__ x, const float* __restrict__ w1,
                       const float* __restrict__ b1, const float* __restrict__ w2,
                       const float* __restrict__ b2, float* __restrict__ out)
{
    __shared__ alignas(16) char lds[2 * 49152];

    const int tid  = threadIdx.x;
    const int lane = tid & 63;
    const int wid  = tid >> 6;
    const int wm   = wid >> 2;
    const int wn   = wid & 3;

    const int nwg = gridDim.x;
    const int bid = (blockIdx.x & 7) * (nwg >> 3) + (blockIdx.x >> 3);
    const int mt  = bid & 15;
    const int nt  = bid >> 4;

    const int lk  = lane & 15;
    const int lg  = lane >> 4;
    const int swz = (lane & 7) << 4;

    const int a_row  = tid >> 3;
    const int a_col8 = tid & 7;
    const int b_ib = ((tid >> 5) & 15) << 2;
    const int b_nb = (tid & 31) << 2;

    const float* pa  = x  + (size_t)(mt * 128 + a_row) * DIN_ + a_col8 * 8;
    const float* pb1 = w1 + (size_t)b_ib * NP_ + (size_t)nt * 128 + b_nb;
    const float* pb2 = w2 + (size_t)b_ib * NP_ + (size_t)nt * 128 + b_nb;

    const int aswz   = (a_col8 * 16) ^ ((a_row & 7) << 4);
    const int aoffw0 = a_row * 128 + aswz;
    const int aoffw1 = (a_row + 64) * 128 + aswz;

    int aoff[4], boff1[2], boff2[2];
#pragma unroll
    for (int fm = 0; fm < 4; ++fm) aoff[fm] = (wm * 64 + fm * 16 + lk) * 128;
#pragma unroll
    for (int fn = 0; fn < 2; ++fn) {
        const int n = wn * 32 + fn * 16 + lk;
        boff1[fn] = 16384 + n * 128;
        boff2[fn] = 32768 + n * 128;
    }
    const int kp0 = (lg * 16) ^ swz;
    const int kp1 = (64 + lg * 16) ^ swz;

    f32x4 acc1[4][2], acc2[4][2];
#pragma unroll
    for (int i = 0; i < 4; ++i)
#pragma unroll
        for (int j = 0; j < 2; ++j) {
            acc1[i][j] = (f32x4){0.f, 0.f, 0.f, 0.f};
            acc2[i][j] = (f32x4){0.f, 0.f, 0.f, 0.f};
        }

    f32x4 rA[4], rB1[4], rB2[4];

    auto LOAD = [&](int kt) {
        const float* a0 = pa + kt * 64;
        rA[0] = *(const f32x4*)(a0);
        rA[1] = *(const f32x4*)(a0 + 4);
        rA[2] = *(const f32x4*)(a0 + (size_t)64 * DIN_);
        rA[3] = *(const f32x4*)(a0 + (size_t)64 * DIN_ + 4);
        const float* q1 = pb1 + (size_t)kt * 64 * NP_;
        const float* q2 = pb2 + (size_t)kt * 64 * NP_;
#pragma unroll
        for (int j = 0; j < 4; ++j) {
            rB1[j] = *(const f32x4*)(q1 + (size_t)j * NP_);
            rB2[j] = *(const f32x4*)(q2 + (size_t)j * NP_);
        }
    };

    auto STORE = [&](char* s) {
        *(bf16x8*)(s + aoffw0) = cvt8(rA[0], rA[1]);
        *(bf16x8*)(s + aoffw1) = cvt8(rA[2], rA[3]);
        char* s1 = s + 16384;
        char* s2 = s + 32768;
#pragma unroll
        for (int c = 0; c < 4; ++c) {
            const int n   = b_nb + c;
            const int off = n * 128 + ((b_ib * 2) ^ ((n & 7) << 4));
            bf16x4 v1, v2;
            v1[0] = (bf16)rB1[0][c]; v1[1] = (bf16)rB1[1][c];
            v1[2] = (bf16)rB1[2][c]; v1[3] = (bf16)rB1[3][c];
            v2[0] = (bf16)rB2[0][c]; v2[1] = (bf16)rB2[1][c];
            v2[2] = (bf16)rB2[2][c]; v2[3] = (bf16)rB2[3][c];
            *(bf16x4*)(s1 + off) = v1;
            *(bf16x4*)(s2 + off) = v2;
        }
    };

    auto COMPUTE = [&](const char* s) {
#pragma unroll
        for (int kb = 0; kb < 2; ++kb) {
            const int kp = kb ? kp1 : kp0;
            bf16x8 a[4], u[2], v[2];
#pragma unroll
            for (int fm = 0; fm < 4; ++fm) a[fm] = *(const bf16x8*)(s + aoff[fm] + kp);
#pragma unroll
            for (int fn = 0; fn < 2; ++fn) u[fn] = *(const bf16x8*)(s + boff1[fn] + kp);
#pragma unroll
            for (int fn = 0; fn < 2; ++fn) v[fn] = *(const bf16x8*)(s + boff2[fn] + kp);
#pragma unroll
            for (int fm = 0; fm < 4; ++fm)
#pragma unroll
                for (int fn = 0; fn < 2; ++fn) {
                    acc1[fm][fn] = __builtin_amdgcn_mfma_f32_16x16x32_bf16(a[fm], u[fn], acc1[fm][fn], 0, 0, 0);
                    acc2[fm][fn] = __builtin_amdgcn_mfma_f32_16x16x32_bf16(a[fm], v[fn], acc2[fm][fn], 0, 0, 0);
                }
        }
    };

    char* buf0 = lds;
    char* buf1 = lds + 49152;

    LOAD(0);
    STORE(buf0);
    __syncthreads();

    for (int kt = 0; kt < 32; ++kt) {
        if (kt + 1 < 32) LOAD(kt + 1);
        COMPUTE((kt & 1) ? buf1 : buf0);
        if (kt + 1 < 32) {
            STORE((kt & 1) ? buf0 : buf1);
            __syncthreads();
        }
    }

    const int obase = nt * 8 + wn * 2;
#pragma unroll
    for (int fn = 0; fn < 2; ++fn) {
        const int o = obase + fn;
        const float bb1 = b1[(size_t)o * 16 + lk];
        const float bb2 = b2[o];
#pragma unroll
        for (int fm = 0; fm < 4; ++fm) {
#pragma unroll
            for (int j = 0; j < 4; ++j) {
                float g = fmaxf(acc1[fm][fn][j] + bb1, 0.f);
                float p = g * acc2[fm][fn][j];
                p += __shfl_xor(p, 1);
                p += __shfl_xor(p, 2);
                p += __shfl_xor(p, 4);
                p += __shfl_xor(p, 8);
                if (lk == 0) {
                    const int brow = mt * 128 + wm * 64 + fm * 16 + lg * 4 + j;
                    out[(size_t)brow * DOUT_ + o] = p + bb2;
                }
            }
        }
    }
}

extern "C" void kernel_launch(void* const* d_in, const int* in_sizes, int n_in,
                              void* d_out, int out_size, void* d_ws, size_t ws_size,
                              hipStream_t stream) {
    (void)in_sizes; (void)n_in; (void)out_size;
    const float* x  = (const float*)d_in[0];
    const float* w1 = (const float*)d_in[1];
    const float* b1 = (const float*)d_in[2];
    const float* w2 = (const float*)d_in[3];
    const float* b2 = (const float*)d_in[4];
    float* out = (float*)d_out;

    const size_t XB   = (size_t)DIN_ * DIN_ * 2;            // 8 MB   (x bf16)
    const size_t WT   = (size_t)NP_ * DIN_ * 2;             // 128 MB (each wt)
    const size_t NEED = XB + 2 * WT;                        // 264 MB

    if (ws_size >= NEED) {
        bf16* xb  = (bf16*)d_ws;
        bf16* w1t = (bf16*)((char*)d_ws + XB);
        bf16* w2t = (bf16*)((char*)d_ws + XB + WT);
        hipLaunchKernelGGL(xcvt,   dim3(2048),       dim3(256),  0, stream, x, xb);
        hipLaunchKernelGGL(wtrans, dim3(512, 32, 2), dim3(256),  0, stream, w1, w2, w1t, w2t);
        hipLaunchKernelGGL(mix2_gemm2b, dim3(2048),  dim3(1024), 0, stream, xb, w1t, w2t, b1, b2, out);
    } else {
        hipLaunchKernelGGL(mix2_fused_direct, dim3(4096), dim3(512), 0, stream, x, w1, b1, w2, b2, out);
    }
}